// Round 1
// baseline (271.429 us; speedup 1.0000x reference)
//
#include <hip/hip_runtime.h>
#include <hip/hip_bf16.h>
#include <stdint.h>

// MHA: B=2, S=2048, D=1024, H=16, dk=64.  All GEMM-shaped work in bf16 MFMA.
// Pipeline: conv(x,W)->bf16 | QKV gemm (scale 1/8 folded into Wq,bq) |
//           flash attention (online softmax, swapped QK^T) | O-proj gemm -> f32.

#define LOG2E 1.4426950408889634f

typedef float f32x4 __attribute__((ext_vector_type(4)));
typedef short bf16x8 __attribute__((ext_vector_type(8)));
typedef short bf16x4 __attribute__((ext_vector_type(4)));

__device__ __forceinline__ unsigned short f2bf(float f) {
  union { float f; unsigned int u; } v; v.f = f;
  unsigned int r = v.u + 0x7fffu + ((v.u >> 16) & 1u);   // RNE
  return (unsigned short)(r >> 16);
}

// ---------- fp32 -> bf16 conversion (optional scale) ----------
__global__ __launch_bounds__(256) void k_conv(const float* __restrict__ src,
                                              unsigned short* __restrict__ dst,
                                              int n4, float scale) {
  int i = blockIdx.x * 256 + threadIdx.x;
  const int stride = gridDim.x * 256;
  for (; i < n4; i += stride) {
    float4 v = ((const float4*)src)[i];
    ushort4 o;
    o.x = f2bf(v.x * scale);
    o.y = f2bf(v.y * scale);
    o.z = f2bf(v.z * scale);
    o.w = f2bf(v.w * scale);
    ((ushort4*)dst)[i] = o;
  }
}

// fused bias vector [3072]: bq*0.125 | bk | bv
__global__ __launch_bounds__(256) void k_bias(const float* __restrict__ bq,
                                              const float* __restrict__ bk,
                                              const float* __restrict__ bv,
                                              float* __restrict__ out) {
  int i = blockIdx.x * 256 + threadIdx.x;
  float v;
  if (i < 1024) v = bq[i] * 0.125f;
  else if (i < 2048) v = bk[i - 1024];
  else v = bv[i - 2048];
  out[i] = v;
}

// ---------- GEMM: C[m][n] = sum_k A[m][k]*B[n][k] + bias[n] ----------
// A [M][1024] bf16, B [N][1024] bf16 (B^T layout, K-contiguous).
// 128x128 tile, 4 waves (2x2), each wave 64x64 via 4x4 16x16x32 MFMA frags.
// MODE 0: write bf16 Q/K/V head-major  [mat][ (b*16+h)*2048+s ][d ]
// MODE 1: write f32 [row][1024] + bias  (final output)
template <int MODE>
__global__ __launch_bounds__(256) void k_gemm(const unsigned short* __restrict__ A,
                                              const unsigned short* __restrict__ B,
                                              const float* __restrict__ bias,
                                              void* __restrict__ outp) {
  __shared__ unsigned short As[128 * 32];
  __shared__ unsigned short Bs[128 * 32];
  const int tid = threadIdx.x;
  const int lane = tid & 63, wid = tid >> 6;
  const int wr = wid >> 1, wc = wid & 1;
  const int r = lane & 15, g = lane >> 4;
  const int bm = blockIdx.x, bn = blockIdx.y;

  const unsigned short* gA = A + (size_t)bm * 128 * 1024;
  const unsigned short* gB = B + (size_t)bn * 128 * 1024;
  const int row0 = tid >> 2, cg = (tid & 3) * 8;

  f32x4 acc[4][4] = {};

  for (int k0 = 0; k0 < 1024; k0 += 32) {
    // reg-staged global->LDS (loads issued before barrier to overlap latency)
    bf16x8 ta0 = *(const bf16x8*)(gA + (size_t)row0 * 1024 + k0 + cg);
    bf16x8 ta1 = *(const bf16x8*)(gA + (size_t)(row0 + 64) * 1024 + k0 + cg);
    bf16x8 tb0 = *(const bf16x8*)(gB + (size_t)row0 * 1024 + k0 + cg);
    bf16x8 tb1 = *(const bf16x8*)(gB + (size_t)(row0 + 64) * 1024 + k0 + cg);
    __syncthreads();
    *(bf16x8*)(As + row0 * 32 + cg) = ta0;
    *(bf16x8*)(As + (row0 + 64) * 32 + cg) = ta1;
    *(bf16x8*)(Bs + row0 * 32 + cg) = tb0;
    *(bf16x8*)(Bs + (row0 + 64) * 32 + cg) = tb1;
    __syncthreads();

    bf16x8 af[4], bfr[4];
#pragma unroll
    for (int i = 0; i < 4; i++) {
      af[i]  = *(const bf16x8*)(As + (wr * 64 + i * 16 + r) * 32 + g * 8);
      bfr[i] = *(const bf16x8*)(Bs + (wc * 64 + i * 16 + r) * 32 + g * 8);
    }
#pragma unroll
    for (int i = 0; i < 4; i++)
#pragma unroll
      for (int j = 0; j < 4; j++)
        acc[i][j] = __builtin_amdgcn_mfma_f32_16x16x32_bf16(af[i], bfr[j], acc[i][j], 0, 0, 0);
  }

  // epilogue: C/D layout col = lane&15, row = (lane>>4)*4 + t
#pragma unroll
  for (int i = 0; i < 4; i++) {
    const int rowb = bm * 128 + wr * 64 + i * 16 + g * 4;
#pragma unroll
    for (int j = 0; j < 4; j++) {
      const int col = bn * 128 + wc * 64 + j * 16 + r;
      const float bv = bias[col];
#pragma unroll
      for (int t = 0; t < 4; t++) {
        const int row = rowb + t;
        const float val = acc[i][j][t] + bv;
        if (MODE == 0) {
          const int mat = col >> 10, nn = col & 1023;
          const int hh = nn >> 6, dd = nn & 63;
          const int bb = row >> 11, ss = row & 2047;
          ((unsigned short*)outp)[(size_t)mat * 4194304 +
              (size_t)((bb * 16 + hh) * 2048 + ss) * 64 + dd] = f2bf(val);
        } else {
          ((float*)outp)[(size_t)row * 1024 + col] = val;
        }
      }
    }
  }
}

// ---------- flash attention ----------
// grid (32 q-tiles, 32 b*h).  Block = 4 waves; wave w owns q-rows q0+w*16+(lane&15).
// Q pre-scaled by 1/8.  Per 32-key tile:
//   S^T = mfma(K_frag, Q_frag): lane holds scores for q = lane&15, keys 4g+t (+16)
//   online softmax (shfl_xor 16/32 across the 4 lanes sharing a q)
//   P -> per-wave LDS -> reload as B-operand (keys 8g..8g+7)
//   o^T += mfma(V^T_chunk, P^T) ; V^T staged in LDS cooperatively
__global__ __launch_bounds__(256) void k_attn(const unsigned short* __restrict__ Q,
                                              const unsigned short* __restrict__ Km,
                                              const unsigned short* __restrict__ V,
                                              unsigned short* __restrict__ merged) {
  __shared__ unsigned short Vt[64 * 32];      // V^T [d][key]
  __shared__ unsigned short Pl[4][16 * 32];   // per-wave P [q][key]
  const int tid = threadIdx.x;
  const int lane = tid & 63, w = tid >> 6;
  const int r = lane & 15, g = lane >> 4;
  const int bh = blockIdx.y;
  const int b = bh >> 4, h = bh & 15;
  const int q0 = blockIdx.x * 64;

  const unsigned short* Qh = Q + (size_t)bh * 2048 * 64;
  const unsigned short* Kh = Km + (size_t)bh * 2048 * 64;
  const unsigned short* Vh = V + (size_t)bh * 2048 * 64;

  const int qrow = q0 + w * 16 + r;
  const bf16x8 bQ0 = *(const bf16x8*)(Qh + (size_t)qrow * 64 + g * 8);
  const bf16x8 bQ1 = *(const bf16x8*)(Qh + (size_t)qrow * 64 + 32 + g * 8);

  float m_run = -INFINITY, l_run = 0.f;
  f32x4 o[4] = {};

  const int vkey = tid >> 3, vdg = (tid & 7) * 8;

  for (int kv0 = 0; kv0 < 2048; kv0 += 32) {
    // cooperative V^T stage (transpose write; known conflicts, fix in later round)
    bf16x8 vv = *(const bf16x8*)(Vh + (size_t)(kv0 + vkey) * 64 + vdg);
#pragma unroll
    for (int j = 0; j < 8; j++) Vt[(vdg + j) * 32 + vkey] = (unsigned short)vv[j];
    __syncthreads();

    // S^T tiles: keys kv0+r (St0) and kv0+16+r (St1), k-dim = dk = 64 (2 MFMAs each)
    f32x4 St0, St1;
    {
      const unsigned short* kp = Kh + (size_t)(kv0 + r) * 64 + g * 8;
      bf16x8 a0 = *(const bf16x8*)(kp);
      bf16x8 a1 = *(const bf16x8*)(kp + 32);
      f32x4 z = {0.f, 0.f, 0.f, 0.f};
      z = __builtin_amdgcn_mfma_f32_16x16x32_bf16(a0, bQ0, z, 0, 0, 0);
      St0 = __builtin_amdgcn_mfma_f32_16x16x32_bf16(a1, bQ1, z, 0, 0, 0);
    }
    {
      const unsigned short* kp = Kh + (size_t)(kv0 + 16 + r) * 64 + g * 8;
      bf16x8 a0 = *(const bf16x8*)(kp);
      bf16x8 a1 = *(const bf16x8*)(kp + 32);
      f32x4 z = {0.f, 0.f, 0.f, 0.f};
      z = __builtin_amdgcn_mfma_f32_16x16x32_bf16(a0, bQ0, z, 0, 0, 0);
      St1 = __builtin_amdgcn_mfma_f32_16x16x32_bf16(a1, bQ1, z, 0, 0, 0);
    }

    // online softmax for q = r (4 lanes per q reduce via xor 16,32)
    float tm = fmaxf(fmaxf(fmaxf(St0[0], St0[1]), fmaxf(St0[2], St0[3])),
                     fmaxf(fmaxf(St1[0], St1[1]), fmaxf(St1[2], St1[3])));
    tm = fmaxf(tm, __shfl_xor(tm, 16));
    tm = fmaxf(tm, __shfl_xor(tm, 32));
    const float mn = fmaxf(m_run, tm);
    const float sc = exp2f((m_run - mn) * LOG2E);
    float p0[4], p1[4], ps = 0.f;
#pragma unroll
    for (int t = 0; t < 4; t++) { p0[t] = exp2f((St0[t] - mn) * LOG2E); ps += p0[t]; }
#pragma unroll
    for (int t = 0; t < 4; t++) { p1[t] = exp2f((St1[t] - mn) * LOG2E); ps += p1[t]; }
    ps += __shfl_xor(ps, 16);
    ps += __shfl_xor(ps, 32);
    l_run = l_run * sc + ps;
    m_run = mn;
#pragma unroll
    for (int c = 0; c < 4; c++)
#pragma unroll
      for (int t = 0; t < 4; t++) o[c][t] *= sc;

    // P -> LDS: lane writes keys 4g..4g+3 and 16+4g..16+4g+3 of row q=r
    bf16x4 pk0, pk1;
#pragma unroll
    for (int t = 0; t < 4; t++) { pk0[t] = (short)f2bf(p0[t]); pk1[t] = (short)f2bf(p1[t]); }
    *(bf16x4*)(&Pl[w][r * 32 + g * 4]) = pk0;
    *(bf16x4*)(&Pl[w][r * 32 + 16 + g * 4]) = pk1;

    // PV: o^T[d][q] += V^T[d][key] * P^T[key][q]
    const bf16x8 pb = *(const bf16x8*)(&Pl[w][r * 32 + g * 8]);
#pragma unroll
    for (int c = 0; c < 4; c++) {
      const bf16x8 av = *(const bf16x8*)(&Vt[(c * 16 + r) * 32 + g * 8]);
      o[c] = __builtin_amdgcn_mfma_f32_16x16x32_bf16(av, pb, o[c], 0, 0, 0);
    }
    __syncthreads();   // protect Vt before next-tile overwrite
  }

  // epilogue: lane holds attn^T[d = c*16+4g+t][q=r]; write merged[b][s][h*64+d]
  const float inv = 1.0f / l_run;
  const size_t base = (size_t)(b * 2048 + qrow) * 1024 + h * 64;
#pragma unroll
  for (int c = 0; c < 4; c++)
#pragma unroll
    for (int t = 0; t < 4; t++)
      merged[base + c * 16 + g * 4 + t] = f2bf(o[c][t] * inv);
}

extern "C" void kernel_launch(void* const* d_in, const int* in_sizes, int n_in,
                              void* d_out, int out_size, void* d_ws, size_t ws_size,
                              hipStream_t stream) {
  const float* x  = (const float*)d_in[0];
  const float* Wq = (const float*)d_in[1];
  const float* bq = (const float*)d_in[2];
  const float* Wk = (const float*)d_in[3];
  const float* bk = (const float*)d_in[4];
  const float* Wv = (const float*)d_in[5];
  const float* bv = (const float*)d_in[6];
  const float* Wo = (const float*)d_in[7];
  const float* bo = (const float*)d_in[8];

  if (ws_size < (size_t)50343936) return;   // need ~48 MB

  unsigned short* ws  = (unsigned short*)d_ws;
  unsigned short* xb  = ws;               // x bf16           [4096][1024]
  unsigned short* Wb  = ws + 4194304;     // Wq/8|Wk|Wv bf16  [3072][1024]
  unsigned short* Wob = ws + 7340032;     // Wo bf16          [1024][1024]
  unsigned short* qkv = ws + 8388608;     // Q|K|V bf16       3x[32][2048][64]
  unsigned short* mrg = ws + 20971520;    // merged bf16      [4096][1024]
  float* biasQ = (float*)(ws + 25165824); // fused qkv bias   [3072] f32

  k_conv<<<dim3(2048), dim3(256), 0, stream>>>(x,  xb,            1048576, 1.0f);
  k_conv<<<dim3(512),  dim3(256), 0, stream>>>(Wq, Wb,            262144, 0.125f);
  k_conv<<<dim3(512),  dim3(256), 0, stream>>>(Wk, Wb + 1048576,  262144, 1.0f);
  k_conv<<<dim3(512),  dim3(256), 0, stream>>>(Wv, Wb + 2097152,  262144, 1.0f);
  k_conv<<<dim3(512),  dim3(256), 0, stream>>>(Wo, Wob,           262144, 1.0f);
  k_bias<<<dim3(12),   dim3(256), 0, stream>>>(bq, bk, bv, biasQ);

  k_gemm<0><<<dim3(32, 24), dim3(256), 0, stream>>>(xb, Wb, biasQ, (void*)qkv);
  k_attn<<<dim3(32, 32), dim3(256), 0, stream>>>(qkv, qkv + 4194304, qkv + 8388608, mrg);
  k_gemm<1><<<dim3(32, 8), dim3(256), 0, stream>>>(mrg, Wob, bo, d_out);
}